// Round 1
// baseline (171.239 us; speedup 1.0000x reference)
//
#include <hip/hip_runtime.h>
#include <cstdint>
#include <cstddef>

// Problem constants
constexpr int N = 4096;
constexpr int B = 32;
constexpr int BN = B * N;             // 131072
constexpr size_t NN = (size_t)N * N;  // 16777216
constexpr int KCHUNKS = 8;            // K-split for the fused GEMM pass
constexpr int KC = N / KCHUNKS;       // 512

constexpr float ALPHA = 0.025f;
constexpr float BETA = 0.00025f;
constexpr float T_NOW = 10.0f;
constexpr float INV_EXP_TAU = 0.02f;          // 1/50
constexpr float INV_TAU_V = 0.98019867f;      // exp(-1/50)
constexpr float INV_TAU_I = 0.36787944f;      // exp(-1)

typedef __attribute__((ext_vector_type(8))) short short8;
typedef __attribute__((ext_vector_type(4))) float f32x4;

__device__ inline unsigned short f2bf(float f) {
  uint32_t u = __float_as_uint(f);
  u += 0x7FFFu + ((u >> 16) & 1u);   // RNE
  return (unsigned short)(u >> 16);
}

// W-update recomputed on the fly (same math as the old pass_b):
//   u = clip(w + BETA - fac_row * exp(|mst_row - mst_col|/50), 0, 1); keep w where w<=0
__device__ inline float wupd(float w, float mrow, float frow, float mcol) {
  float d = fabsf(mrow - mcol);
  float u = w + BETA - frow * __expf(d * INV_EXP_TAU);
  u = fminf(fmaxf(u, 0.0f), 1.0f);
  return (w > 0.0f) ? u : w;
}

// ---------------------------------------------------------------------------
// Pass A: per-neuron spike masks + max_st + rowfac; writes S (f32) and S_bf
// (bf16 copy, the MFMA A-matrix). Also zeroes the SW/SWT accumulators.
// ---------------------------------------------------------------------------
__global__ __launch_bounds__(256) void pass_a(
    const float* __restrict__ mem_pot, const float* __restrict__ mem_pot_p,
    const float* __restrict__ st, float* __restrict__ S_out,
    unsigned short* __restrict__ S_bf,
    uint32_t* __restrict__ maskS, uint32_t* __restrict__ maskSP,
    float* __restrict__ max_st, float* __restrict__ rowfac,
    float4* __restrict__ zero_region /* SW||SWT: 2*BN floats = 65536 float4 */) {
  int j = blockIdx.x * blockDim.x + threadIdx.x;
  if (j >= N) return;

  // zero SW/SWT accumulators (atomicAdd targets for the fused GEMM)
  float4 z = {0.0f, 0.0f, 0.0f, 0.0f};
  #pragma unroll
  for (int k = 0; k < 16; ++k) zero_region[j + k * 4096] = z;

  float stj = st[j];
  uint32_t ms = 0u, msp = 0u;
  float maxv = -3.0e38f;
  #pragma unroll
  for (int b = 0; b < B; ++b) {
    float p = mem_pot[b * N + j];
    float pp = mem_pot_p[b * N + j];
    bool s = (p - 1.0f) > 0.0f;
    bool sp = ((pp - 1.0f) - ALPHA) > 0.0f;
    S_out[b * N + j] = s ? 1.0f : 0.0f;
    S_bf[b * N + j] = s ? 0x3F80u : 0u;   // bf16 1.0 / 0.0
    ms |= (uint32_t)s << b;
    msp |= (uint32_t)sp << b;
    maxv = fmaxf(maxv, s ? T_NOW : stj);
  }
  maskS[j] = ms;
  maskSP[j] = msp;
  max_st[j] = maxv;
  rowfac[j] = msp ? ALPHA : 0.0f;
}

// ---------------------------------------------------------------------------
// Fused pass: W-update recomputed on the fly inside BOTH skinny GEMMs.
//   gemm 0 (blockIdx.z==0): SW[b,j]  += sum_k S[b,k]*Wnew[k,j]   (reads W cols-ish)
//   gemm 1 (blockIdx.z==1): SWT[b,i] += sum_j S[b,j]*Wnew[i,j]   (reads W rows,
//                                       writes W_out — exact 1x coverage)
// Verified MFMA layouts (16x16x32 bf16):
//   A[m=lane&15][k=quad*8+i], B[k=quad*8+i][n=lane&15],
//   C/D: col=lane&15, row=quad*4+reg.
// Accumulation into SW/SWT via f32 atomicAdd (L2-resident 0.5 MB buffers),
// so KCHUNKS can grow for occupancy without partial-buffer traffic.
// ---------------------------------------------------------------------------
__global__ __launch_bounds__(256) void pass_fused(
    const float* __restrict__ W, const unsigned short* __restrict__ S_bf,
    const float* __restrict__ max_st, const float* __restrict__ rowfac,
    float* __restrict__ Wout, float* __restrict__ SW, float* __restrict__ SWT) {
  __shared__ float mstK[KC];
  __shared__ float facK[KC];

  int tid = threadIdx.x;
  int wv = tid >> 6;
  int lane = tid & 63;
  int ntile = blockIdx.x * 4 + wv;     // 0..255
  int j0 = ntile * 16;
  int kbase = blockIdx.y * KC;         // 0..N-KC
  int gemm = blockIdx.z;
  int quad = lane >> 4;
  int nl = lane & 15;

  // stage the k-chunk's row/col vectors in LDS
  for (int t = tid; t < KC; t += 256) {
    mstK[t] = max_st[kbase + t];
    facK[t] = rowfac[kbase + t];
  }
  __syncthreads();

  f32x4 acc0 = {0.f, 0.f, 0.f, 0.f};
  f32x4 acc1 = {0.f, 0.f, 0.f, 0.f};
  const unsigned short* A0p = S_bf + (size_t)nl * N;          // batches 0-15
  const unsigned short* A1p = S_bf + (size_t)(nl + 16) * N;   // batches 16-31

  if (gemm == 0) {
    // element W[k][j0+nl]: row k (mstK/facK), col j0+nl (mj)
    float mj = max_st[j0 + nl];
    #pragma unroll 2
    for (int it = 0; it < KC / 32; ++it) {
      int ko = it * 32 + quad * 8;     // offset within chunk
      int kg = kbase + ko;             // global k
      short8 a0 = *(const short8*)(A0p + kg);
      short8 a1 = *(const short8*)(A1p + kg);
      const float* wp = W + (size_t)kg * N + j0 + nl;
      float4 m4a = *(const float4*)(mstK + ko);
      float4 m4b = *(const float4*)(mstK + ko + 4);
      float4 f4a = *(const float4*)(facK + ko);
      float4 f4b = *(const float4*)(facK + ko + 4);
      float w[8];
      #pragma unroll
      for (int i = 0; i < 8; ++i) w[i] = wp[(size_t)i * N];
      short8 bf;
      bf[0] = (short)f2bf(wupd(w[0], m4a.x, f4a.x, mj));
      bf[1] = (short)f2bf(wupd(w[1], m4a.y, f4a.y, mj));
      bf[2] = (short)f2bf(wupd(w[2], m4a.z, f4a.z, mj));
      bf[3] = (short)f2bf(wupd(w[3], m4a.w, f4a.w, mj));
      bf[4] = (short)f2bf(wupd(w[4], m4b.x, f4b.x, mj));
      bf[5] = (short)f2bf(wupd(w[5], m4b.y, f4b.y, mj));
      bf[6] = (short)f2bf(wupd(w[6], m4b.z, f4b.z, mj));
      bf[7] = (short)f2bf(wupd(w[7], m4b.w, f4b.w, mj));
      acc0 = __builtin_amdgcn_mfma_f32_16x16x32_bf16(a0, bf, acc0, 0, 0, 0);
      acc1 = __builtin_amdgcn_mfma_f32_16x16x32_bf16(a1, bf, acc1, 0, 0, 0);
    }
  } else {
    // element W[j0+nl][k]: row j0+nl (mi, fi), col k (mstK). Writes W_out.
    float mi = max_st[j0 + nl];
    float fi = rowfac[j0 + nl];
    const float* __restrict__ Wr = W + (size_t)(j0 + nl) * N;
    float* __restrict__ Wor = Wout + (size_t)(j0 + nl) * N;
    #pragma unroll 2
    for (int it = 0; it < KC / 32; ++it) {
      int ko = it * 32 + quad * 8;
      int kg = kbase + ko;
      short8 a0 = *(const short8*)(A0p + kg);
      short8 a1 = *(const short8*)(A1p + kg);
      float4 f0 = *(const float4*)(Wr + kg);
      float4 f1 = *(const float4*)(Wr + kg + 4);
      float4 m4a = *(const float4*)(mstK + ko);
      float4 m4b = *(const float4*)(mstK + ko + 4);
      float4 u0, u1;
      u0.x = wupd(f0.x, mi, fi, m4a.x);
      u0.y = wupd(f0.y, mi, fi, m4a.y);
      u0.z = wupd(f0.z, mi, fi, m4a.z);
      u0.w = wupd(f0.w, mi, fi, m4a.w);
      u1.x = wupd(f1.x, mi, fi, m4b.x);
      u1.y = wupd(f1.y, mi, fi, m4b.y);
      u1.z = wupd(f1.z, mi, fi, m4b.z);
      u1.w = wupd(f1.w, mi, fi, m4b.w);
      *(float4*)(Wor + kg) = u0;
      *(float4*)(Wor + kg + 4) = u1;
      short8 bf;
      bf[0] = (short)f2bf(u0.x); bf[1] = (short)f2bf(u0.y);
      bf[2] = (short)f2bf(u0.z); bf[3] = (short)f2bf(u0.w);
      bf[4] = (short)f2bf(u1.x); bf[5] = (short)f2bf(u1.y);
      bf[6] = (short)f2bf(u1.z); bf[7] = (short)f2bf(u1.w);
      acc0 = __builtin_amdgcn_mfma_f32_16x16x32_bf16(a0, bf, acc0, 0, 0, 0);
      acc1 = __builtin_amdgcn_mfma_f32_16x16x32_bf16(a1, bf, acc1, 0, 0, 0);
    }
  }

  // C/D: col = lane&15 (n), row = quad*4+reg (batch). Atomic-accumulate.
  float* dst = (gemm == 0) ? SW : SWT;
  #pragma unroll
  for (int r = 0; r < 4; ++r) {
    atomicAdd(dst + (size_t)(quad * 4 + r) * N + j0 + nl, acc0[r]);
    atomicAdd(dst + (size_t)(16 + quad * 4 + r) * N + j0 + nl, acc1[r]);
  }
}

// ---------------------------------------------------------------------------
// Pass D: integrate + leak + reset + refractory (SW/SWT now direct reads).
// ---------------------------------------------------------------------------
__global__ __launch_bounds__(256) void pass_d(
    const float* __restrict__ inp, const float* __restrict__ mem_pot,
    const float* __restrict__ mem_cur, const float* __restrict__ mem_pot_p,
    const float* __restrict__ mem_cur_p, const int* __restrict__ refrac_in,
    const uint32_t* __restrict__ maskS, const uint32_t* __restrict__ maskSP,
    const float* __restrict__ SWbuf, const float* __restrict__ SWTbuf,
    float* __restrict__ pot_out, float* __restrict__ cur_out,
    float* __restrict__ potp_out, float* __restrict__ curp_out,
    float* __restrict__ refrac_out) {
  int e = blockIdx.x * 256 + threadIdx.x;
  int b = e >> 12;
  int j = e & (N - 1);

  float SW = SWbuf[e];
  float SWT = SWTbuf[e];

  int r = refrac_in[e];
  int rd = (r > 0) ? (r - 1) : r;
  bool active = (rd == 0);
  bool s = (maskS[j] >> b) & 1u;
  bool sp = (maskSP[j] >> b) & 1u;
  float cur = mem_cur[e], pot = mem_pot[e];
  float curp = mem_cur_p[e], potp = mem_pot_p[e];

  float cur_n = active ? (inp[e] + SW + cur) : cur;
  float curp_n = active ? (SWT + curp) : curp;
  float pot_n = active ? (cur_n + pot) : pot;
  float potp_n = active ? (curp_n + potp) : potp;

  pot_n *= INV_TAU_V;
  cur_n *= INV_TAU_I;
  potp_n *= INV_TAU_V;
  curp_n *= INV_TAU_I;

  if (s) pot_n = 0.0f;
  if (sp) potp_n = 0.0f;
  int rn = s ? 2 : rd;

  pot_out[e] = pot_n;
  cur_out[e] = cur_n;
  potp_out[e] = potp_n;
  curp_out[e] = curp_n;
  refrac_out[e] = (float)rn;
}

// ---------------------------------------------------------------------------
extern "C" void kernel_launch(void* const* d_in, const int* in_sizes, int n_in,
                              void* d_out, int out_size, void* d_ws, size_t ws_size,
                              hipStream_t stream) {
  const float* inp = (const float*)d_in[0];
  const float* W = (const float*)d_in[1];
  const float* mem_pot = (const float*)d_in[2];
  const float* mem_cur = (const float*)d_in[3];
  const float* mem_pot_p = (const float*)d_in[4];
  const float* mem_cur_p = (const float*)d_in[5];
  const float* st = (const float*)d_in[6];
  const int* refrac = (const int*)d_in[7];

  float* out = (float*)d_out;
  float* S_out = out;
  float* pot_out = out + BN;
  float* W_out = out + 2 * (size_t)BN;
  float* cur_out = W_out + NN;
  float* potp_out = cur_out + BN;
  float* curp_out = potp_out + BN;
  float* refrac_out = curp_out + BN;

  // Workspace layout (16B-aligned), ~1.3 MB total
  uint32_t* maskS = (uint32_t*)d_ws;                      // 16 KB
  uint32_t* maskSP = maskS + N;                           // 16 KB
  float* max_st = (float*)(maskSP + N);                   // 16 KB
  float* rowfac = max_st + N;                             // 16 KB
  unsigned short* S_bf = (unsigned short*)(rowfac + N);   // 256 KB
  float* SW = (float*)(S_bf + BN);                        // 512 KB
  float* SWT = SW + BN;                                   // 512 KB (contiguous w/ SW)

  pass_a<<<N / 256, 256, 0, stream>>>(mem_pot, mem_pot_p, st, S_out, S_bf,
                                      maskS, maskSP, max_st, rowfac,
                                      (float4*)SW);
  pass_fused<<<dim3(64, KCHUNKS, 2), 256, 0, stream>>>(W, S_bf, max_st, rowfac,
                                                       W_out, SW, SWT);
  pass_d<<<BN / 256, 256, 0, stream>>>(inp, mem_pot, mem_cur, mem_pot_p,
                                       mem_cur_p, refrac, maskS, maskSP,
                                       SW, SWT, pot_out, cur_out,
                                       potp_out, curp_out, refrac_out);
}